// Round 2
// baseline (1334.606 us; speedup 1.0000x reference)
//
#include <hip/hip_runtime.h>
#include <math.h>

#define BATCH 2048
#define NPOS 4
#define NNEG 128
#define DIM 1024
#define NS (NNEG + 1)   // 129 samples per row (last positive + 128 negatives)
#define EPSV 1e-6f

__device__ __forceinline__ float dot4(float4 a, float4 b) {
    return a.x * b.x + a.y * b.y + a.z * b.z + a.w * b.w;
}

// One block per batch row b. 4 waves; wave w owns negatives [w*32, w*32+32)
// (contiguous 128 KB stream per wave). 2-sample manual unroll: 8 KB of loads
// in flight per wave; 4 independent shuffle-reduce chains interleaved.
__global__ __launch_bounds__(256) void contrastive_row_kernel(
    const float* __restrict__ anchor,     // [B, 1, D]
    const float* __restrict__ positives,  // [B, P, D]
    const float* __restrict__ negatives,  // [B, N, D]
    float* __restrict__ partial)          // [B] per-row loss
{
    const int b    = blockIdx.x;
    const int tid  = threadIdx.x;
    const int lane = tid & 63;
    const int wave = tid >> 6;

    __shared__ float s_sim[NS];
    __shared__ float s_red[8];

    const float4* a_ptr = (const float4*)(anchor + (size_t)b * DIM);
    const float4 a0 = a_ptr[lane];
    const float4 a1 = a_ptr[64 + lane];
    const float4 a2 = a_ptr[128 + lane];
    const float4 a3 = a_ptr[192 + lane];

    // every wave computes ||a|| itself — no barrier needed
    float an = dot4(a0, a0) + dot4(a1, a1) + dot4(a2, a2) + dot4(a3, a3);
    #pragma unroll
    for (int off = 32; off; off >>= 1) an += __shfl_xor(an, off);
    const float na = fmaxf(sqrtf(an), EPSV);

    // sample 0 = last positive, handled by wave 0 (overlaps other waves' loop)
    if (wave == 0) {
        const float4* row = (const float4*)(positives + ((size_t)b * NPOS + (NPOS - 1)) * DIM);
        float4 v0 = row[lane];
        float4 v1 = row[64 + lane];
        float4 v2 = row[128 + lane];
        float4 v3 = row[192 + lane];
        float d = dot4(a0, v0) + dot4(a1, v1) + dot4(a2, v2) + dot4(a3, v3);
        float n = dot4(v0, v0) + dot4(v1, v1) + dot4(v2, v2) + dot4(v3, v3);
        #pragma unroll
        for (int off = 32; off; off >>= 1) {
            d += __shfl_xor(d, off);
            n += __shfl_xor(n, off);
        }
        if (lane == 0) s_sim[0] = d / (na * fmaxf(sqrtf(n), EPSV));
    }

    const float4* negs = (const float4*)(negatives + (size_t)b * NNEG * DIM);
    const int base = wave * 32;

    #pragma unroll
    for (int i = 0; i < 32; i += 2) {
        const float4* r0 = negs + (size_t)(base + i)     * (DIM / 4);
        const float4* r1 = negs + (size_t)(base + i + 1) * (DIM / 4);
        float4 u0 = r0[lane], u1 = r0[64 + lane], u2 = r0[128 + lane], u3 = r0[192 + lane];
        float4 w0 = r1[lane], w1 = r1[64 + lane], w2 = r1[128 + lane], w3 = r1[192 + lane];

        float d0 = dot4(a0, u0) + dot4(a1, u1) + dot4(a2, u2) + dot4(a3, u3);
        float n0 = dot4(u0, u0) + dot4(u1, u1) + dot4(u2, u2) + dot4(u3, u3);
        float d1 = dot4(a0, w0) + dot4(a1, w1) + dot4(a2, w2) + dot4(a3, w3);
        float n1 = dot4(w0, w0) + dot4(w1, w1) + dot4(w2, w2) + dot4(w3, w3);

        // 4 independent reduce chains interleaved — ds latency overlaps
        #pragma unroll
        for (int off = 32; off; off >>= 1) {
            d0 += __shfl_xor(d0, off);
            d1 += __shfl_xor(d1, off);
            n0 += __shfl_xor(n0, off);
            n1 += __shfl_xor(n1, off);
        }
        if (lane == 0) {
            s_sim[1 + base + i]     = d0 / (na * fmaxf(sqrtf(n0), EPSV));
            s_sim[1 + base + i + 1] = d1 / (na * fmaxf(sqrtf(n1), EPSV));
        }
    }
    __syncthreads();

    // log-softmax over s_sim[0..NS-1]; loss_b = -(sim[0] - m - log(sum_exp))
    float v = (tid < NS) ? s_sim[tid] : -INFINITY;
    float m = v;
    #pragma unroll
    for (int off = 32; off; off >>= 1) m = fmaxf(m, __shfl_xor(m, off));
    if (lane == 0) s_red[wave] = m;
    __syncthreads();
    if (tid == 0) {
        s_red[4] = fmaxf(fmaxf(s_red[0], s_red[1]), fmaxf(s_red[2], s_red[3]));
    }
    __syncthreads();
    m = s_red[4];

    float e = (tid < NS) ? expf(v - m) : 0.0f;
    #pragma unroll
    for (int off = 32; off; off >>= 1) e += __shfl_xor(e, off);
    if (lane == 0) s_red[wave] = e;
    __syncthreads();
    if (tid == 0) {
        float sum = s_red[0] + s_red[1] + s_red[2] + s_red[3];
        partial[b] = -(s_sim[0] - m - logf(sum));
    }
}

__global__ __launch_bounds__(256) void reduce_mean_kernel(
    const float* __restrict__ partial, float* __restrict__ out)
{
    __shared__ float s_red[4];
    const int tid  = threadIdx.x;
    const int lane = tid & 63;
    const int wave = tid >> 6;
    float s = 0.0f;
    for (int i = tid; i < BATCH; i += 256) s += partial[i];
    #pragma unroll
    for (int off = 32; off; off >>= 1) s += __shfl_xor(s, off);
    if (lane == 0) s_red[wave] = s;
    __syncthreads();
    if (tid == 0) {
        out[0] = (s_red[0] + s_red[1] + s_red[2] + s_red[3]) / (float)BATCH;
    }
}

extern "C" void kernel_launch(void* const* d_in, const int* in_sizes, int n_in,
                              void* d_out, int out_size, void* d_ws, size_t ws_size,
                              hipStream_t stream) {
    const float* anchor    = (const float*)d_in[0];
    const float* positives = (const float*)d_in[1];
    const float* negatives = (const float*)d_in[2];
    float* out     = (float*)d_out;
    float* partial = (float*)d_ws;   // BATCH floats = 8 KB scratch

    contrastive_row_kernel<<<BATCH, 256, 0, stream>>>(anchor, positives, negatives, partial);
    reduce_mean_kernel<<<1, 256, 0, stream>>>(partial, out);
}